// Round 1
// baseline (1003.574 us; speedup 1.0000x reference)
//
#include <hip/hip_runtime.h>

#define DFEAT 64

// ---- degree: cnt[dst] += 1 ----
__global__ void degree_kernel(const int* __restrict__ dst, int n_edges,
                              float* __restrict__ cnt) {
    int e = blockIdx.x * blockDim.x + threadIdx.x;
    if (e < n_edges) atomicAdd(&cnt[dst[e]], 1.0f);
}

// ---- scatter-add: agg[dst] += x[src], 64 lanes per edge ----
__global__ void scatter_kernel(const int* __restrict__ src,
                               const int* __restrict__ dst,
                               int n_edges,
                               const float* __restrict__ x,
                               float* __restrict__ agg) {
    long long idx = (long long)blockIdx.x * blockDim.x + threadIdx.x;
    int e = (int)(idx >> 6);
    int j = (int)(idx & 63);
    if (e >= n_edges) return;
    int s = src[e];
    int d = dst[e];
    atomicAdd(&agg[(long long)d * DFEAT + j], x[(long long)s * DFEAT + j]);
}

// ---- fused linear: out = act( (agg/max(cnt,1)) @ Wl + xin @ Wr + b ) ----
template <bool RELU>
__global__ __launch_bounds__(256) void linear_kernel(
    const float* __restrict__ agg, const float* __restrict__ cnt,
    const float* __restrict__ xin, const float* __restrict__ Wl,
    const float* __restrict__ Wr, const float* __restrict__ b,
    float* __restrict__ out, int n_nodes) {
    __shared__ float sWl[DFEAT * DFEAT];
    __shared__ float sWr[DFEAT * DFEAT];
    __shared__ float sA[4][DFEAT];
    __shared__ float sX[4][DFEAT];

    for (int i = threadIdx.x; i < DFEAT * DFEAT; i += 256) {
        sWl[i] = Wl[i];
        sWr[i] = Wr[i];
    }

    int local = threadIdx.x >> 6;   // 0..3 (node within block)
    int j = threadIdx.x & 63;       // output column
    int node = blockIdx.x * 4 + local;
    bool valid = node < n_nodes;
    int nclamp = valid ? node : (n_nodes - 1);

    float inv = 1.0f / fmaxf(cnt[nclamp], 1.0f);
    sA[local][j] = agg[(long long)nclamp * DFEAT + j] * inv;
    sX[local][j] = xin[(long long)nclamp * DFEAT + j];
    __syncthreads();

    float acc = b[j];
#pragma unroll
    for (int k = 0; k < DFEAT; ++k) {
        acc += sA[local][k] * sWl[k * DFEAT + j];
        acc += sX[local][k] * sWr[k * DFEAT + j];
    }
    if (RELU) acc = fmaxf(acc, 0.0f);
    if (valid) out[(long long)node * DFEAT + j] = acc;
}

extern "C" void kernel_launch(void* const* d_in, const int* in_sizes, int n_in,
                              void* d_out, int out_size, void* d_ws, size_t ws_size,
                              hipStream_t stream) {
    const float* x   = (const float*)d_in[0];
    const int*   ei  = (const int*)d_in[1];
    const float* Wl1 = (const float*)d_in[2];
    const float* Wr1 = (const float*)d_in[3];
    const float* b1  = (const float*)d_in[4];
    const float* Wl2 = (const float*)d_in[5];
    const float* Wr2 = (const float*)d_in[6];
    const float* b2  = (const float*)d_in[7];
    float* out = (float*)d_out;

    int n_nodes = in_sizes[0] / DFEAT;   // 100000
    int n_edges = in_sizes[1] / 2;       // 1600000
    const int* src = ei;
    const int* dstv = ei + n_edges;

    char* ws = (char*)d_ws;
    size_t cnt_bytes = ((size_t)n_nodes * sizeof(float) + 255) & ~(size_t)255;
    float* cnt = (float*)ws;
    float* agg = (float*)(ws + cnt_bytes);
    float* h   = agg + (size_t)n_nodes * DFEAT;

    size_t agg_bytes = (size_t)n_nodes * DFEAT * sizeof(float);

    hipMemsetAsync(cnt, 0, (size_t)n_nodes * sizeof(float), stream);
    hipMemsetAsync(agg, 0, agg_bytes, stream);

    int eb = (n_edges + 255) / 256;
    degree_kernel<<<eb, 256, 0, stream>>>(dstv, n_edges, cnt);

    long long sthreads = (long long)n_edges * 64;
    int sb = (int)((sthreads + 255) / 256);
    scatter_kernel<<<sb, 256, 0, stream>>>(src, dstv, n_edges, x, agg);

    int nb = (n_nodes + 3) / 4;
    linear_kernel<true><<<nb, 256, 0, stream>>>(agg, cnt, x, Wl1, Wr1, b1, h, n_nodes);

    hipMemsetAsync(agg, 0, agg_bytes, stream);
    scatter_kernel<<<sb, 256, 0, stream>>>(src, dstv, n_edges, h, agg);

    linear_kernel<false><<<nb, 256, 0, stream>>>(agg, cnt, h, Wl2, Wr2, b2, out, n_nodes);
}

// Round 2
// 542.490 us; speedup vs baseline: 1.8499x; 1.8499x over previous
//
#include <hip/hip_runtime.h>

#define DFEAT 64

// ---- histogram: cnt[dst]++ ----
__global__ void hist_kernel(const int* __restrict__ dst, int n_edges,
                            int* __restrict__ cnt) {
    int e = blockIdx.x * blockDim.x + threadIdx.x;
    if (e < n_edges) atomicAdd(&cnt[dst[e]], 1);
}

// ---- scan pass 1: per-block (1024 elems) exclusive scan + block totals ----
__global__ __launch_bounds__(256) void scan1_kernel(const int* __restrict__ in, int n,
                                                    int* __restrict__ out,
                                                    int* __restrict__ sums) {
    __shared__ int sdata[256];
    int blk = blockIdx.x;
    int base = blk * 1024;
    int t = threadIdx.x;
    int v[4];
    int local = 0;
#pragma unroll
    for (int k = 0; k < 4; ++k) {
        int i = base + t * 4 + k;
        v[k] = (i < n) ? in[i] : 0;
        local += v[k];
    }
    sdata[t] = local;
    __syncthreads();
    for (int off = 1; off < 256; off <<= 1) {
        int x = (t >= off) ? sdata[t - off] : 0;
        __syncthreads();
        sdata[t] += x;
        __syncthreads();
    }
    int excl = sdata[t] - local;
    if (t == 255) sums[blk] = sdata[255];
    int run = excl;
#pragma unroll
    for (int k = 0; k < 4; ++k) {
        int i = base + t * 4 + k;
        if (i < n) out[i] = run;
        run += v[k];
    }
}

// ---- scan pass 2: exclusive scan of block totals (nsums <= 256), total -> *total ----
__global__ __launch_bounds__(256) void scan2_kernel(int* __restrict__ sums, int nsums,
                                                    int* __restrict__ total) {
    __shared__ int sdata[256];
    int t = threadIdx.x;
    int v = (t < nsums) ? sums[t] : 0;
    sdata[t] = v;
    __syncthreads();
    for (int off = 1; off < 256; off <<= 1) {
        int x = (t >= off) ? sdata[t - off] : 0;
        __syncthreads();
        sdata[t] += x;
        __syncthreads();
    }
    if (t < nsums) sums[t] = sdata[t] - v;
    if (t == 255) *total = sdata[255];
}

// ---- scan pass 3: add block offsets; duplicate into cursor ----
__global__ __launch_bounds__(256) void scan3_kernel(int* __restrict__ out, int n,
                                                    const int* __restrict__ sums,
                                                    int* __restrict__ cursor) {
    int blk = blockIdx.x;
    int base = blk * 1024;
    int off = sums[blk];
    for (int k = threadIdx.x; k < 1024; k += 256) {
        int i = base + k;
        if (i < n) {
            int val = out[i] + off;
            out[i] = val;
            cursor[i] = val;
        }
    }
}

// ---- fill: counting-sort edges by dst; store src per slot ----
__global__ void fill_kernel(const int* __restrict__ src, const int* __restrict__ dst,
                            int n_edges, int* __restrict__ cursor,
                            int* __restrict__ col_src) {
    int e = blockIdx.x * blockDim.x + threadIdx.x;
    if (e < n_edges) {
        int d = dst[e];
        int pos = atomicAdd(&cursor[d], 1);
        col_src[pos] = src[e];
    }
}

// ---- fused SAGE layer: gather-mean + two matvecs + bias (+ReLU) ----
// block = 256 threads = 4 waves; wave w handles node blockIdx.x*4+w; lane j = feature
template <bool RELU>
__global__ __launch_bounds__(256) void sage_kernel(
    const int* __restrict__ row_ptr, const int* __restrict__ col_src,
    const float* __restrict__ xin, const float* __restrict__ Wl,
    const float* __restrict__ Wr, const float* __restrict__ b,
    float* __restrict__ out, int n_nodes) {
    __shared__ float sWl[DFEAT * DFEAT];
    __shared__ float sWr[DFEAT * DFEAT];
    __shared__ float sA[4][DFEAT];
    __shared__ float sX[4][DFEAT];

    for (int i = threadIdx.x; i < DFEAT * DFEAT; i += 256) {
        sWl[i] = Wl[i];
        sWr[i] = Wr[i];
    }

    int w = threadIdx.x >> 6;
    int j = threadIdx.x & 63;
    int node = blockIdx.x * 4 + w;
    bool valid = node < n_nodes;
    int nc = valid ? node : (n_nodes - 1);

    int start = row_ptr[nc];
    int end = row_ptr[nc + 1];
    float sum = 0.0f;
    for (int base = start; base < end; base += 64) {
        int m = end - base;
        if (m > 64) m = 64;
        int sreg = col_src[base + (j < m ? j : 0)];
        int i = 0;
        for (; i + 4 <= m; i += 4) {
            int s0 = __shfl(sreg, i);
            int s1 = __shfl(sreg, i + 1);
            int s2 = __shfl(sreg, i + 2);
            int s3 = __shfl(sreg, i + 3);
            float v0 = xin[(long long)s0 * DFEAT + j];
            float v1 = xin[(long long)s1 * DFEAT + j];
            float v2 = xin[(long long)s2 * DFEAT + j];
            float v3 = xin[(long long)s3 * DFEAT + j];
            sum += v0; sum += v1; sum += v2; sum += v3;
        }
        for (; i < m; ++i) {
            int s = __shfl(sreg, i);
            sum += xin[(long long)s * DFEAT + j];
        }
    }
    int deg = end - start;
    float mean = (deg > 0) ? sum * (1.0f / (float)deg) : 0.0f;
    sA[w][j] = mean;
    sX[w][j] = xin[(long long)nc * DFEAT + j];
    __syncthreads();   // covers weight staging + sA/sX visibility (no early returns)

    float acc = b[j];
#pragma unroll
    for (int k = 0; k < DFEAT; ++k) {
        acc += sA[w][k] * sWl[k * DFEAT + j];
        acc += sX[w][k] * sWr[k * DFEAT + j];
    }
    if (RELU) acc = fmaxf(acc, 0.0f);
    if (valid) out[(long long)node * DFEAT + j] = acc;
}

extern "C" void kernel_launch(void* const* d_in, const int* in_sizes, int n_in,
                              void* d_out, int out_size, void* d_ws, size_t ws_size,
                              hipStream_t stream) {
    const float* x   = (const float*)d_in[0];
    const int*   ei  = (const int*)d_in[1];
    const float* Wl1 = (const float*)d_in[2];
    const float* Wr1 = (const float*)d_in[3];
    const float* b1  = (const float*)d_in[4];
    const float* Wl2 = (const float*)d_in[5];
    const float* Wr2 = (const float*)d_in[6];
    const float* b2  = (const float*)d_in[7];
    float* out = (float*)d_out;

    int n_nodes = in_sizes[0] / DFEAT;   // 100000
    int n_edges = in_sizes[1] / 2;       // 1600000
    const int* src  = ei;
    const int* dstv = ei + n_edges;

    auto align = [](size_t v) { return (v + 255) & ~(size_t)255; };
    char* ws = (char*)d_ws;
    int* cnt     = (int*)ws;                         ws += align((size_t)n_nodes * 4);
    int* row_ptr = (int*)ws;                         ws += align(((size_t)n_nodes + 1) * 4);
    int* cursor  = (int*)ws;                         ws += align((size_t)n_nodes * 4);
    int* sums    = (int*)ws;                         ws += align(256 * 4);
    int* col_src = (int*)ws;                         ws += align((size_t)n_edges * 4);
    float* h     = (float*)ws;

    hipMemsetAsync(cnt, 0, (size_t)n_nodes * 4, stream);

    int eb = (n_edges + 255) / 256;
    hist_kernel<<<eb, 256, 0, stream>>>(dstv, n_edges, cnt);

    int nscan = (n_nodes + 1023) / 1024;             // 98 blocks (<=256 required)
    scan1_kernel<<<nscan, 256, 0, stream>>>(cnt, n_nodes, row_ptr, sums);
    scan2_kernel<<<1, 256, 0, stream>>>(sums, nscan, row_ptr + n_nodes);
    scan3_kernel<<<nscan, 256, 0, stream>>>(row_ptr, n_nodes, sums, cursor);

    fill_kernel<<<eb, 256, 0, stream>>>(src, dstv, n_edges, cursor, col_src);

    int nb = (n_nodes + 3) / 4;
    sage_kernel<true><<<nb, 256, 0, stream>>>(row_ptr, col_src, x, Wl1, Wr1, b1, h, n_nodes);
    sage_kernel<false><<<nb, 256, 0, stream>>>(row_ptr, col_src, h, Wl2, Wr2, b2, out, n_nodes);
}

// Round 3
// 400.354 us; speedup vs baseline: 2.5067x; 1.3550x over previous
//
#include <hip/hip_runtime.h>

#define DFEAT 64

// ---- histogram: cnt[dst]++ ----
__global__ void hist_kernel(const int* __restrict__ dst, int n_edges,
                            int* __restrict__ cnt) {
    int e = blockIdx.x * blockDim.x + threadIdx.x;
    if (e < n_edges) atomicAdd(&cnt[dst[e]], 1);
}

// ---- scan pass 1: per-block (1024 elems) exclusive scan + block totals ----
__global__ __launch_bounds__(256) void scan1_kernel(const int* __restrict__ in, int n,
                                                    int* __restrict__ out,
                                                    int* __restrict__ sums) {
    __shared__ int sdata[256];
    int blk = blockIdx.x;
    int base = blk * 1024;
    int t = threadIdx.x;
    int v[4];
    int local = 0;
#pragma unroll
    for (int k = 0; k < 4; ++k) {
        int i = base + t * 4 + k;
        v[k] = (i < n) ? in[i] : 0;
        local += v[k];
    }
    sdata[t] = local;
    __syncthreads();
    for (int off = 1; off < 256; off <<= 1) {
        int x = (t >= off) ? sdata[t - off] : 0;
        __syncthreads();
        sdata[t] += x;
        __syncthreads();
    }
    int excl = sdata[t] - local;
    if (t == 255) sums[blk] = sdata[255];
    int run = excl;
#pragma unroll
    for (int k = 0; k < 4; ++k) {
        int i = base + t * 4 + k;
        if (i < n) out[i] = run;
        run += v[k];
    }
}

// ---- scan pass 2: exclusive scan of block totals (nsums <= 256) ----
__global__ __launch_bounds__(256) void scan2_kernel(int* __restrict__ sums, int nsums,
                                                    int* __restrict__ total) {
    __shared__ int sdata[256];
    int t = threadIdx.x;
    int v = (t < nsums) ? sums[t] : 0;
    sdata[t] = v;
    __syncthreads();
    for (int off = 1; off < 256; off <<= 1) {
        int x = (t >= off) ? sdata[t - off] : 0;
        __syncthreads();
        sdata[t] += x;
        __syncthreads();
    }
    if (t < nsums) sums[t] = sdata[t] - v;
    if (t == 255) *total = sdata[255];
}

// ---- scan pass 3: add block offsets; duplicate into cursor ----
__global__ __launch_bounds__(256) void scan3_kernel(int* __restrict__ out, int n,
                                                    const int* __restrict__ sums,
                                                    int* __restrict__ cursor) {
    int blk = blockIdx.x;
    int base = blk * 1024;
    int off = sums[blk];
    for (int k = threadIdx.x; k < 1024; k += 256) {
        int i = base + k;
        if (i < n) {
            int val = out[i] + off;
            out[i] = val;
            cursor[i] = val;
        }
    }
}

// ---- fill: counting-sort edges by dst; store src per slot ----
__global__ void fill_kernel(const int* __restrict__ src, const int* __restrict__ dst,
                            int n_edges, int* __restrict__ cursor,
                            int* __restrict__ col_src) {
    int e = blockIdx.x * blockDim.x + threadIdx.x;
    if (e < n_edges) {
        int d = dst[e];
        int pos = atomicAdd(&cursor[d], 1);
        col_src[pos] = src[e];
    }
}

// ---- fused SAGE layer: gather-mean + two matvecs + bias (+ReLU) ----
// block = 512 threads = 8 waves = 8 nodes; lane split: group g=lane>>4, pos p=lane&15
// gather: each instruction loads float4 of 4 different neighbor rows (1KB/instr)
template <bool RELU>
__global__ __launch_bounds__(512, 8) void sage_kernel(
    const int* __restrict__ row_ptr, const int* __restrict__ col_src,
    const float* __restrict__ xin, const float* __restrict__ Wl,
    const float* __restrict__ Wr, const float* __restrict__ b,
    float* __restrict__ out, int n_nodes) {
    __shared__ float sWl[DFEAT * DFEAT];
    __shared__ float sWr[DFEAT * DFEAT];
    __shared__ float sA[8][DFEAT];
    __shared__ float sX[8][DFEAT];

    {
        const float4* Wl4 = (const float4*)Wl;
        const float4* Wr4 = (const float4*)Wr;
        float4* sWl4 = (float4*)sWl;
        float4* sWr4 = (float4*)sWr;
        for (int i = threadIdx.x; i < DFEAT * DFEAT / 4; i += 512) {
            sWl4[i] = Wl4[i];
            sWr4[i] = Wr4[i];
        }
    }

    int w = threadIdx.x >> 6;       // wave = node within block
    int lane = threadIdx.x & 63;
    int g = lane >> 4;              // neighbor-group 0..3
    int p = lane & 15;              // float4 slot within row
    int node = blockIdx.x * 8 + w;
    bool valid = node < n_nodes;
    int nc = valid ? node : (n_nodes - 1);

    // own row (lin_r input) + bias, issued early to overlap gather
    float4 xrow = *(const float4*)&xin[(size_t)nc * DFEAT + p * 4];
    float bj = b[lane];

    int start = row_ptr[nc];
    int end = row_ptr[nc + 1];
    int deg = end - start;

    float4 acc4 = make_float4(0.f, 0.f, 0.f, 0.f);
    for (int base = start; base < end; base += 64) {
        int m = end - base;
        if (m > 64) m = 64;
        int sreg = col_src[base + (lane < m ? lane : 0)];
        for (int i = 0; i < m; i += 16) {
            int n0 = i + g, n1 = i + 4 + g, n2 = i + 8 + g, n3 = i + 12 + g;
            int s0 = __shfl(sreg, n0 < m ? n0 : 0);
            int s1 = __shfl(sreg, n1 < m ? n1 : 0);
            int s2 = __shfl(sreg, n2 < m ? n2 : 0);
            int s3 = __shfl(sreg, n3 < m ? n3 : 0);
            float4 v0 = *(const float4*)&xin[(size_t)s0 * DFEAT + p * 4];
            float4 v1 = *(const float4*)&xin[(size_t)s1 * DFEAT + p * 4];
            float4 v2 = *(const float4*)&xin[(size_t)s2 * DFEAT + p * 4];
            float4 v3 = *(const float4*)&xin[(size_t)s3 * DFEAT + p * 4];
            float f0 = (n0 < m) ? 1.f : 0.f;
            float f1 = (n1 < m) ? 1.f : 0.f;
            float f2 = (n2 < m) ? 1.f : 0.f;
            float f3 = (n3 < m) ? 1.f : 0.f;
            acc4.x += v0.x * f0 + v1.x * f1 + v2.x * f2 + v3.x * f3;
            acc4.y += v0.y * f0 + v1.y * f1 + v2.y * f2 + v3.y * f3;
            acc4.z += v0.z * f0 + v1.z * f1 + v2.z * f2 + v3.z * f3;
            acc4.w += v0.w * f0 + v1.w * f1 + v2.w * f2 + v3.w * f3;
        }
    }

    // reduce across the 4 neighbor-groups (lanes p, p+16, p+32, p+48)
    acc4.x += __shfl_xor(acc4.x, 16); acc4.x += __shfl_xor(acc4.x, 32);
    acc4.y += __shfl_xor(acc4.y, 16); acc4.y += __shfl_xor(acc4.y, 32);
    acc4.z += __shfl_xor(acc4.z, 16); acc4.z += __shfl_xor(acc4.z, 32);
    acc4.w += __shfl_xor(acc4.w, 16); acc4.w += __shfl_xor(acc4.w, 32);

    float invd = (deg > 0) ? 1.0f / (float)deg : 0.0f;
    if (g == 0) {
        float4 mv = make_float4(acc4.x * invd, acc4.y * invd,
                                acc4.z * invd, acc4.w * invd);
        *(float4*)&sA[w][p * 4] = mv;
    }
    if (g == 1) {
        *(float4*)&sX[w][p * 4] = xrow;
    }
    __syncthreads();   // covers weight staging + sA/sX (no early returns)

    float acc = bj;
#pragma unroll
    for (int k = 0; k < DFEAT; ++k) {
        acc += sA[w][k] * sWl[k * DFEAT + lane];
        acc += sX[w][k] * sWr[k * DFEAT + lane];
    }
    if (RELU) acc = fmaxf(acc, 0.0f);
    if (valid) out[(size_t)node * DFEAT + lane] = acc;
}

extern "C" void kernel_launch(void* const* d_in, const int* in_sizes, int n_in,
                              void* d_out, int out_size, void* d_ws, size_t ws_size,
                              hipStream_t stream) {
    const float* x   = (const float*)d_in[0];
    const int*   ei  = (const int*)d_in[1];
    const float* Wl1 = (const float*)d_in[2];
    const float* Wr1 = (const float*)d_in[3];
    const float* b1  = (const float*)d_in[4];
    const float* Wl2 = (const float*)d_in[5];
    const float* Wr2 = (const float*)d_in[6];
    const float* b2  = (const float*)d_in[7];
    float* out = (float*)d_out;

    int n_nodes = in_sizes[0] / DFEAT;   // 100000
    int n_edges = in_sizes[1] / 2;       // 1600000
    const int* src  = ei;
    const int* dstv = ei + n_edges;

    auto align = [](size_t v) { return (v + 255) & ~(size_t)255; };
    char* ws = (char*)d_ws;
    int* cnt     = (int*)ws;                         ws += align((size_t)n_nodes * 4);
    int* row_ptr = (int*)ws;                         ws += align(((size_t)n_nodes + 1) * 4);
    int* cursor  = (int*)ws;                         ws += align((size_t)n_nodes * 4);
    int* sums    = (int*)ws;                         ws += align(256 * 4);
    int* col_src = (int*)ws;                         ws += align((size_t)n_edges * 4);
    float* h     = (float*)ws;

    hipMemsetAsync(cnt, 0, (size_t)n_nodes * 4, stream);

    int eb = (n_edges + 255) / 256;
    hist_kernel<<<eb, 256, 0, stream>>>(dstv, n_edges, cnt);

    int nscan = (n_nodes + 1023) / 1024;             // 98 blocks (<=256 required)
    scan1_kernel<<<nscan, 256, 0, stream>>>(cnt, n_nodes, row_ptr, sums);
    scan2_kernel<<<1, 256, 0, stream>>>(sums, nscan, row_ptr + n_nodes);
    scan3_kernel<<<nscan, 256, 0, stream>>>(row_ptr, n_nodes, sums, cursor);

    fill_kernel<<<eb, 256, 0, stream>>>(src, dstv, n_edges, cursor, col_src);

    int nb = (n_nodes + 7) / 8;
    sage_kernel<true><<<nb, 512, 0, stream>>>(row_ptr, col_src, x, Wl1, Wr1, b1, h, n_nodes);
    sage_kernel<false><<<nb, 512, 0, stream>>>(row_ptr, col_src, h, Wl2, Wr2, b2, out, n_nodes);
}